// Round 8
// baseline (42.875 us; speedup 1.0000x reference)
//
#include <hip/hip_runtime.h>

#define NROWS 8192
#define DIM 128
#define NT 64        // 128-row bands
#define NCHUNK 544   // sum over bands rt of ceil((64-rt)/4)
#define CHUNK 4

typedef _Float16 f16x8 __attribute__((ext_vector_type(8)));
typedef _Float16 f16x2 __attribute__((ext_vector_type(2)));
typedef float f32x16 __attribute__((ext_vector_type(16)));

#define L2E 1.4426950408889634f  // log2(e)

#define AS1(p) ((const __attribute__((address_space(1))) void*)(p))
#define AS3(p) ((__attribute__((address_space(3))) void*)(p))

// ---------------------------------------------------------------------------
// Kernel 1: per-row L2 normalize (fp32, as reference). 1024 threads = 16
// waves, one wave per row, 512 blocks. Emits zh (f16 normalized z1) and
// sposB (per-block partial of the positive term). ||n1||^2 = 1 +- 3e-7 by
// construction -> absorbed into the epilogue constant (rounds 6/7 verified).
// ---------------------------------------------------------------------------
__global__ __launch_bounds__(1024) void fmicl_normalize(
    const float* __restrict__ z1, const float* __restrict__ z2,
    _Float16* __restrict__ zh, float* __restrict__ sposB) {
  const int wid = threadIdx.x >> 6;
  const int lane = threadIdx.x & 63;
  const int row = blockIdx.x * 16 + wid;
  const float2 a = ((const float2*)(z1 + (size_t)row * DIM))[lane];
  const float2 b = ((const float2*)(z2 + (size_t)row * DIM))[lane];
  float s1 = a.x * a.x + a.y * a.y;
  float s2 = b.x * b.x + b.y * b.y;
#pragma unroll
  for (int off = 32; off; off >>= 1) {
    s1 += __shfl_xor(s1, off);
    s2 += __shfl_xor(s2, off);
  }
  const float inv1 = 1.0f / fmaxf(sqrtf(s1), 1e-12f);
  const float inv2 = 1.0f / fmaxf(sqrtf(s2), 1e-12f);
  const float n1x = a.x * inv1, n1y = a.y * inv1;
  const float n2x = b.x * inv2, n2y = b.y * inv2;
  const float dx = n1x - n2x, dy = n1y - n2y;
  float dp = dx * dx + dy * dy;
#pragma unroll
  for (int off = 32; off; off >>= 1) dp += __shfl_xor(dp, off);
  f16x2 h;
  h.x = (_Float16)n1x;
  h.y = (_Float16)n1y;
  *(f16x2*)(zh + (size_t)row * DIM + 2 * lane) = h;
  __shared__ float sposL[16];
  if (lane == 0)
    sposL[wid] = logf(expf(-0.5f * dp) + 1e-8f) + 1.0f;  // f'(g_pos)
  __syncthreads();
  if (threadIdx.x == 0) {
    float s = 0.0f;
#pragma unroll
    for (int k = 0; k < 16; ++k) s += sposL[k];
    sposB[blockIdx.x] = s;
  }
}

// ---------------------------------------------------------------------------
// Stage one 128-row B panel (32 KiB) into LDS via global_load_lds width=16.
// LDS dest linear; global source pre-swizzled (granule col ^= row&15) so the
// read-side XOR is the same involution (rule #21; rounds 3-7 verified).
// 4 wave-instructions per wave (32 total = 32 KiB).
// ---------------------------------------------------------------------------
__device__ __forceinline__ void stageB(const _Float16* __restrict__ zh,
                                       _Float16* buf, int ct, int wid,
                                       int lane) {
  const _Float16* base = zh + ((size_t)ct << 7) * DIM;
#pragma unroll
  for (int it = 0; it < 4; ++it) {
    const int P = it * 8 + wid;          // wave-uniform 4-row group 0..31
    const int R = P * 4 + (lane >> 4);   // row 0..127
    const int cs = (lane & 15) ^ (R & 15);
    __builtin_amdgcn_global_load_lds(AS1(base + (size_t)R * DIM + cs * 8),
                                     AS3(buf + P * 512), 16, 0, 0);
  }
}

// ---------------------------------------------------------------------------
// Kernel 2: persistent row-band chunks, B-double-buffered, A-in-registers.
// 512 threads = 8 waves (2M x 4N); wave tile 64M x 32N = 2 MFMA chains
// sharing one B-frag per K-step (1 ds_read_b128 -> 2 MFMA: 0.5 KB LDS/MFMA).
// Each block owns <=4 consecutive tiles (ct0..) of band rt:
//   prologue: A-frags (128 rows x wave's granules) global->REG (64 VGPR,
//             L2-resident), stage B(tile0) -> buf0.
//   per tile: issue stage B(t+1) -> other buf; s_waitcnt vmcnt(4) (counted,
//             loads stay in flight over the barrier - T4); s_barrier;
//             8x {ds_read b128; 2 MFMA}; exp2 epilogue; s_barrier.
// Diag tile (ct==rt) w=1 whole-tile (contains both orderings), off-diag w=2.
// LDS 64 KiB + VGPR<=128 (launch_bounds 512,4) -> 2 blocks/CU.
// XCD-chunked grid swizzle (544 = 8*68, bijective). No atomics.
// ---------------------------------------------------------------------------
__global__ __launch_bounds__(512, 4) void fmicl_pairwise(
    const _Float16* __restrict__ zh, float* __restrict__ pairP) {
  __shared__ _Float16 B0[128 * DIM];  // 32 KiB
  __shared__ _Float16 B1[128 * DIM];  // 32 KiB
  __shared__ float wsum[8];

  const int tid = threadIdx.x;
  const int lane = tid & 63;
  const int wid = tid >> 6;

  // XCD swizzle: 544 = 8 * 68 (bijective)
  const int c = (blockIdx.x & 7) * (NCHUNK / 8) + (blockIdx.x >> 3);

  // ---- decode chunk id -> (band rt, chunk k within band) ----
  int rt = 0, accum = 0;
#pragma unroll 1
  for (; rt < 64; ++rt) {
    const int nc = (64 - rt + 3) >> 2;
    if (c < accum + nc) break;
    accum += nc;
  }
  const int k = c - accum;
  const int ct0 = rt + k * CHUNK;
  const int len = min(CHUNK, 64 - ct0);

  const int l31 = lane & 31;
  const int lhi = lane >> 5;
  const int m = wid >> 2;  // 0..1  (64-row half of the 128-row band)
  const int n = wid & 3;   // 0..3  (32-col quarter of the 128-col tile)
  const int i0 = rt << 7;

  // ---- A-frags straight to registers (no LDS): rows i0+m*64+{0,32}+l31,
  //      granules 2ks+lhi (16B each) — exactly the MFMA A-frag bytes. ----
  uint4 areg0[8], areg1[8];
  {
    const uint4* r0 = (const uint4*)(zh + (size_t)(i0 + m * 64 + l31) * DIM);
    const uint4* r1 = r0 + 32 * (DIM / 8);
#pragma unroll
    for (int ks = 0; ks < 8; ++ks) {
      areg0[ks] = r0[2 * ks + lhi];
      areg1[ks] = r1[2 * ks + lhi];
    }
  }

  stageB(zh, B0, ct0, wid, lane);  // prologue stage of tile 0

  float gsum = 0.0f;
#pragma unroll 1
  for (int t = 0; t < len; ++t) {
    _Float16* curB = (t & 1) ? B1 : B0;
    if (t + 1 < len) {
      stageB(zh, (t & 1) ? B0 : B1, ct0 + t + 1, wid, lane);
      asm volatile("s_waitcnt vmcnt(4)" ::: "memory");  // cur done; next flies
    } else {
      asm volatile("s_waitcnt vmcnt(0)" ::: "memory");
    }
    __builtin_amdgcn_s_barrier();
    __builtin_amdgcn_sched_barrier(0);

    // ---- compute: 8 K-steps, 1 B-read feeds 2 MFMA chains ----
    const uint4* B4 = (const uint4*)curB;
    const int rb = n * 32 + l31;
    f32x16 a0 = {}, a1 = {};
#pragma unroll
    for (int ks = 0; ks < 8; ++ks) {
      const uint4 vb = B4[rb * 16 + ((2 * ks + lhi) ^ (rb & 15))];
      const f16x8 bf = __builtin_bit_cast(f16x8, vb);
      a0 = __builtin_amdgcn_mfma_f32_32x32x16_f16(
          __builtin_bit_cast(f16x8, areg0[ks]), bf, a0, 0, 0, 0);
      a1 = __builtin_amdgcn_mfma_f32_32x32x16_f16(
          __builtin_bit_cast(f16x8, areg1[ks]), bf, a1, 0, 0, 0);
    }

    // ---- epilogue: g = exp2(fma(log2e, dot, -log2e)) == exp(-d2/2) ----
    // C/D layout (32x32): col=lane&31, row=(reg&3)+8*(reg>>2)+4*(lane>>5)
    const int ct = ct0 + t;
    float tsum = 0.0f;
    {  // chain 0: rows [i0+m*64, +32)
      const bool dsub = (ct == rt) && (n == 2 * m);  // wave-uniform
      if (dsub) {
#pragma unroll
        for (int r = 0; r < 16; ++r) {
          const float e = __builtin_amdgcn_exp2f(fmaf(L2E, a0[r], -L2E));
          const int mloc = (r & 3) + 4 * lhi + 8 * (r >> 2);
          tsum += (mloc != l31) ? e : 0.0f;
        }
      } else {
#pragma unroll
        for (int r = 0; r < 16; ++r)
          tsum += __builtin_amdgcn_exp2f(fmaf(L2E, a0[r], -L2E));
      }
    }
    {  // chain 1: rows [i0+m*64+32, +32)
      const bool dsub = (ct == rt) && (n == 2 * m + 1);
      if (dsub) {
#pragma unroll
        for (int r = 0; r < 16; ++r) {
          const float e = __builtin_amdgcn_exp2f(fmaf(L2E, a1[r], -L2E));
          const int mloc = (r & 3) + 4 * lhi + 8 * (r >> 2);
          tsum += (mloc != l31) ? e : 0.0f;
        }
      } else {
#pragma unroll
        for (int r = 0; r < 16; ++r)
          tsum += __builtin_amdgcn_exp2f(fmaf(L2E, a1[r], -L2E));
      }
    }
    gsum += (ct == rt) ? tsum : (tsum + tsum);  // off-diag tiles mirrored x2

    __builtin_amdgcn_s_barrier();  // reads of curB done before its re-stage
  }

  // ---- per-chunk reduction -> pairP[c] ----
#pragma unroll
  for (int off = 32; off; off >>= 1) gsum += __shfl_xor(gsum, off);
  if (lane == 0) wsum[wid] = gsum;
  __syncthreads();
  if (tid == 0) {
    float s = 0.0f;
#pragma unroll
    for (int q = 0; q < 8; ++q) s += wsum[q];
    pairP[c] = s;
  }
}

// ---------------------------------------------------------------------------
// Kernel 3: single-block fused reduce + assemble scalar (deterministic
// fixed-order tree). star_neg = g + EPS exactly, so
// star_mean = negSum/(N(N-1)) + EPS.
// ---------------------------------------------------------------------------
__global__ void fmicl_reduce(const float* __restrict__ pairP,
                             const float* __restrict__ sposB,
                             float* __restrict__ out) {
  const int t = threadIdx.x;  // 1024 threads = 16 waves
  double nsum = (t < NCHUNK) ? (double)pairP[t] : 0.0;
  double psum = (t < 512) ? (double)sposB[t] : 0.0;
#pragma unroll
  for (int off = 32; off; off >>= 1) {
    nsum += __shfl_xor(nsum, off);
    psum += __shfl_xor(psum, off);
  }
  __shared__ double ls[2][16];
  const int lane = t & 63;
  const int wid = t >> 6;
  if (lane == 0) {
    ls[0][wid] = nsum;
    ls[1][wid] = psum;
  }
  __syncthreads();
  if (t == 0) {
    double nn = 0.0, pp = 0.0;
#pragma unroll
    for (int q = 0; q < 16; ++q) {
      nn += ls[0][q];
      pp += ls[1][q];
    }
    const double pos_mean = pp / (double)NROWS;
    const double star_mean = nn / ((double)NROWS * (double)(NROWS - 1)) + 1e-8;
    out[0] = (float)(-pos_mean + 1.5 * star_mean);
  }
}

extern "C" void kernel_launch(void* const* d_in, const int* in_sizes, int n_in,
                              void* d_out, int out_size, void* d_ws,
                              size_t ws_size, hipStream_t stream) {
  const float* z1 = (const float*)d_in[0];
  const float* z2 = (const float*)d_in[1];
  float* out = (float*)d_out;
  char* ws = (char*)d_ws;

  // ws layout (every slot rewritten every call; no memset needed):
  //   [0)     pairP float[544]    (pad to 4096)
  //   [4096)  sposB float[512]    (2048 B)
  //   [6144)  zh    f16[8192*128] (2 MiB, 16B-aligned)
  float* pairP = (float*)(ws + 0);
  float* sposB = (float*)(ws + 4096);
  _Float16* zh = (_Float16*)(ws + 6144);

  fmicl_normalize<<<512, 1024, 0, stream>>>(z1, z2, zh, sposB);
  fmicl_pairwise<<<NCHUNK, 512, 0, stream>>>(zh, pairP);
  fmicl_reduce<<<1, 1024, 0, stream>>>(pairP, sposB, out);
}

// Round 9
// 30.001 us; speedup vs baseline: 1.4291x; 1.4291x over previous
//
#include <hip/hip_runtime.h>

#define NROWS 8192
#define DIM 128
#define NT 64      // 128x128 tiles per side
#define NBLK 512   // pairwise blocks; block c owns 4(+1) consecutive tiles

typedef _Float16 f16x8 __attribute__((ext_vector_type(8)));
typedef _Float16 f16x2 __attribute__((ext_vector_type(2)));
typedef float f32x16 __attribute__((ext_vector_type(16)));

#define L2E 1.4426950408889634f  // log2(e)

#define AS1(p) ((const __attribute__((address_space(1))) void*)(p))
#define AS3(p) ((__attribute__((address_space(3))) void*)(p))

// ---------------------------------------------------------------------------
// Kernel 1: per-row L2 normalize (fp32, as reference). 1024 threads = 16
// waves, one wave per row, 512 blocks. Emits zh (f16 normalized z1) and
// sposB (per-block partial of the positive term). ||n1||^2 = 1 +- 3e-7 by
// construction -> absorbed into the epilogue constant (rounds 6-8 verified).
// ---------------------------------------------------------------------------
__global__ __launch_bounds__(1024) void fmicl_normalize(
    const float* __restrict__ z1, const float* __restrict__ z2,
    _Float16* __restrict__ zh, float* __restrict__ sposB) {
  const int wid = threadIdx.x >> 6;
  const int lane = threadIdx.x & 63;
  const int row = blockIdx.x * 16 + wid;
  const float2 a = ((const float2*)(z1 + (size_t)row * DIM))[lane];
  const float2 b = ((const float2*)(z2 + (size_t)row * DIM))[lane];
  float s1 = a.x * a.x + a.y * a.y;
  float s2 = b.x * b.x + b.y * b.y;
#pragma unroll
  for (int off = 32; off; off >>= 1) {
    s1 += __shfl_xor(s1, off);
    s2 += __shfl_xor(s2, off);
  }
  const float inv1 = 1.0f / fmaxf(sqrtf(s1), 1e-12f);
  const float inv2 = 1.0f / fmaxf(sqrtf(s2), 1e-12f);
  const float n1x = a.x * inv1, n1y = a.y * inv1;
  const float n2x = b.x * inv2, n2y = b.y * inv2;
  const float dx = n1x - n2x, dy = n1y - n2y;
  float dp = dx * dx + dy * dy;
#pragma unroll
  for (int off = 32; off; off >>= 1) dp += __shfl_xor(dp, off);
  f16x2 h;
  h.x = (_Float16)n1x;
  h.y = (_Float16)n1y;
  *(f16x2*)(zh + (size_t)row * DIM + 2 * lane) = h;
  __shared__ float sposL[16];
  if (lane == 0)
    sposL[wid] = logf(expf(-0.5f * dp) + 1e-8f) + 1.0f;  // f'(g_pos)
  __syncthreads();
  if (threadIdx.x == 0) {
    float s = 0.0f;
#pragma unroll
    for (int k = 0; k < 16; ++k) s += sposL[k];
    sposB[blockIdx.x] = s;
  }
}

// ---------------------------------------------------------------------------
// Stage one 128-row B panel (32 KiB) into LDS via global_load_lds width=16.
// LDS dest linear; global source pre-swizzled (granule col ^= row&15) so the
// read-side XOR is the same involution (rule #21; rounds 3-8 verified).
// 4 instructions per wave (32 KiB total with 8 waves).
// ---------------------------------------------------------------------------
__device__ __forceinline__ void stageB(const _Float16* __restrict__ zh,
                                       _Float16* buf, int ct, int wid,
                                       int lane) {
  const _Float16* base = zh + ((size_t)ct << 7) * DIM;
#pragma unroll
  for (int it = 0; it < 4; ++it) {
    const int P = it * 8 + wid;          // wave-uniform 4-row group 0..31
    const int R = P * 4 + (lane >> 4);   // row 0..127
    const int cs = (lane & 15) ^ (R & 15);
    __builtin_amdgcn_global_load_lds(AS1(base + (size_t)R * DIM + cs * 8),
                                     AS3(buf + P * 512), 16, 0, 0);
  }
}

// ---------------------------------------------------------------------------
// Kernel 2: balanced flat-chunk pipeline. 512 blocks; block c owns tiles
// [4c+nx(c), +len) of the flat upper-triangular list (len=5 when c%16==0,
// else 4; nx = extras before c). Coords advance by increment (ct++, wrap ->
// next band) — no per-tile decode. 8 waves (4M x 2N); wave = 32 A-rows in
// REGISTERS (areg[8], reloaded only on band crossing) x 64 B-cols from LDS:
// per K-step 2 ds_read_b128 -> 2 MFMA. B double-buffered (2 x 32 KiB LDS);
// next tile staged BEFORE compute with counted s_waitcnt vmcnt(4) so its
// loads stay in flight across the barrier (T4). ~105 VGPR < 128 cap ->
// 2 blocks/CU (64 KiB LDS): one block's compute overlaps the other's stage.
// XCD swizzle (bid&7)*64+bid>>3: exactly 260 tiles AND 64 blocks per XCD.
// Epilogue: g = exp2(fma(log2e,dot,-log2e)) == exp(-d2/2) for unit rows;
// off-diag tiles weighted x2, diagonal masked. No atomics.
// ---------------------------------------------------------------------------
__global__ __launch_bounds__(512, 4) void fmicl_pairwise(
    const _Float16* __restrict__ zh, float* __restrict__ pairP) {
  __shared__ _Float16 B0[128 * DIM];  // 32 KiB
  __shared__ _Float16 B1[128 * DIM];  // 32 KiB
  __shared__ float wsum[8];

  const int tid = threadIdx.x;
  const int lane = tid & 63;
  const int wid = tid >> 6;
  const int l31 = lane & 31;
  const int lhi = lane >> 5;
  const int m = wid >> 1;  // 0..3: 32-row block of the band
  const int n = wid & 1;   // 0..1: 64-col half of the tile

  // XCD-chunked swizzle (512 = 8*64, bijective; 260 tiles per XCD)
  const int c = (blockIdx.x & 7) * 64 + (blockIdx.x >> 3);
  const int nx = (c + 15) >> 4;             // len-5 chunks before c
  const int base = 4 * c + nx;
  const int len = 4 + ((c & 15) == 0 ? 1 : 0);

  // ---- decode base -> (rt, ct); C(r) = r*NT - r(r-1)/2 ----
  int rt = (int)(64.5f - sqrtf(64.5f * 64.5f - 2.0f * (float)base));
  if (rt < 0) rt = 0;
  while (rt > 0 && (rt * NT - (rt * (rt - 1)) / 2) > base) --rt;
  while (((rt + 1) * NT - ((rt + 1) * rt) / 2) <= base) ++rt;
  int ctt = rt + (base - (rt * NT - (rt * (rt - 1)) / 2));
  int rtt = rt;

  stageB(zh, B0, ctt, wid, lane);  // prologue stage of tile 0

  uint4 areg[8];
  int cur_rt = -1;
  float gsum = 0.0f;

#pragma unroll 1
  for (int t = 0; t < len; ++t) {
    // ---- A-regs: reload only on band crossing (once per block usually) ----
    if (rtt != cur_rt) {
      cur_rt = rtt;
      const uint4* ar =
          (const uint4*)(zh + (size_t)((rtt << 7) + m * 32 + l31) * DIM);
#pragma unroll
      for (int ks = 0; ks < 8; ++ks) areg[ks] = ar[2 * ks + lhi];
    }
    // ---- next tile coords; issue its stage before computing this one ----
    int nrt = rtt, nct = ctt + 1;
    if (nct == NT) { ++nrt; nct = nrt; }
    if (t + 1 < len) {
      stageB(zh, (t & 1) ? B0 : B1, nct, wid, lane);
      // all but the newest 4 loads (= next tile's stage) complete: current
      // B-panel + any A-reload are in. Next stage flies across the barrier.
      asm volatile("s_waitcnt vmcnt(4)" ::: "memory");
    } else {
      asm volatile("s_waitcnt vmcnt(0)" ::: "memory");
    }
    __builtin_amdgcn_s_barrier();
    __builtin_amdgcn_sched_barrier(0);

    // ---- compute: 8 K-steps, 2 B-reads -> 2 MFMA (A from registers) ----
    const uint4* B4 = (const uint4*)((t & 1) ? B1 : B0);
    const int rb0 = n * 64 + l31;
    const int rb1 = n * 64 + 32 + l31;
    f32x16 acc0 = {}, acc1 = {};
#pragma unroll
    for (int ks = 0; ks < 8; ++ks) {
      const int kg = 2 * ks + lhi;
      const uint4 vb0 = B4[rb0 * 16 + (kg ^ (rb0 & 15))];
      const uint4 vb1 = B4[rb1 * 16 + (kg ^ (rb1 & 15))];
      const f16x8 af = __builtin_bit_cast(f16x8, areg[ks]);
      acc0 = __builtin_amdgcn_mfma_f32_32x32x16_f16(
          af, __builtin_bit_cast(f16x8, vb0), acc0, 0, 0, 0);
      acc1 = __builtin_amdgcn_mfma_f32_32x32x16_f16(
          af, __builtin_bit_cast(f16x8, vb1), acc1, 0, 0, 0);
    }

    // ---- epilogue: g = exp2(log2e*dot - log2e) == exp(-d2/2) ----
    // C/D layout (32x32): col=lane&31, row=(reg&3)+8*(reg>>2)+4*(lane>>5)
    float tsum = 0.0f;
    {  // chain 0: cols [n*64, +32); diag sub-block iff m == 2n
      const bool dsub = (rtt == ctt) && (m == 2 * n);
      if (dsub) {
#pragma unroll
        for (int r = 0; r < 16; ++r) {
          const float e = __builtin_amdgcn_exp2f(fmaf(L2E, acc0[r], -L2E));
          const int mloc = (r & 3) + 4 * lhi + 8 * (r >> 2);
          tsum += (mloc != l31) ? e : 0.0f;
        }
      } else {
#pragma unroll
        for (int r = 0; r < 16; ++r)
          tsum += __builtin_amdgcn_exp2f(fmaf(L2E, acc0[r], -L2E));
      }
    }
    {  // chain 1: cols [n*64+32, +32); diag sub-block iff m == 2n+1
      const bool dsub = (rtt == ctt) && (m == 2 * n + 1);
      if (dsub) {
#pragma unroll
        for (int r = 0; r < 16; ++r) {
          const float e = __builtin_amdgcn_exp2f(fmaf(L2E, acc1[r], -L2E));
          const int mloc = (r & 3) + 4 * lhi + 8 * (r >> 2);
          tsum += (mloc != l31) ? e : 0.0f;
        }
      } else {
#pragma unroll
        for (int r = 0; r < 16; ++r)
          tsum += __builtin_amdgcn_exp2f(fmaf(L2E, acc1[r], -L2E));
      }
    }
    gsum += (rtt == ctt) ? tsum : (tsum + tsum);  // off-diag mirrored x2

    __builtin_amdgcn_s_barrier();  // buf reads done before its re-stage
    rtt = nrt;
    ctt = nct;
  }

  // ---- per-block reduction -> pairP[c] ----
#pragma unroll
  for (int off = 32; off; off >>= 1) gsum += __shfl_xor(gsum, off);
  if (lane == 0) wsum[wid] = gsum;
  __syncthreads();
  if (tid == 0) {
    float s = 0.0f;
#pragma unroll
    for (int q = 0; q < 8; ++q) s += wsum[q];
    pairP[c] = s;
  }
}

// ---------------------------------------------------------------------------
// Kernel 3: single-block fused reduce + assemble scalar (deterministic
// fixed-order tree). star_neg = g + EPS exactly, so
// star_mean = negSum/(N(N-1)) + EPS.
// ---------------------------------------------------------------------------
__global__ void fmicl_reduce(const float* __restrict__ pairP,
                             const float* __restrict__ sposB,
                             float* __restrict__ out) {
  const int t = threadIdx.x;  // 1024 threads = 16 waves
  double nsum = (t < NBLK) ? (double)pairP[t] : 0.0;
  double psum = (t < 512) ? (double)sposB[t] : 0.0;
#pragma unroll
  for (int off = 32; off; off >>= 1) {
    nsum += __shfl_xor(nsum, off);
    psum += __shfl_xor(psum, off);
  }
  __shared__ double ls[2][16];
  const int lane = t & 63;
  const int wid = t >> 6;
  if (lane == 0) {
    ls[0][wid] = nsum;
    ls[1][wid] = psum;
  }
  __syncthreads();
  if (t == 0) {
    double nn = 0.0, pp = 0.0;
#pragma unroll
    for (int q = 0; q < 16; ++q) {
      nn += ls[0][q];
      pp += ls[1][q];
    }
    const double pos_mean = pp / (double)NROWS;
    const double star_mean = nn / ((double)NROWS * (double)(NROWS - 1)) + 1e-8;
    out[0] = (float)(-pos_mean + 1.5 * star_mean);
  }
}

extern "C" void kernel_launch(void* const* d_in, const int* in_sizes, int n_in,
                              void* d_out, int out_size, void* d_ws,
                              size_t ws_size, hipStream_t stream) {
  const float* z1 = (const float*)d_in[0];
  const float* z2 = (const float*)d_in[1];
  float* out = (float*)d_out;
  char* ws = (char*)d_ws;

  // ws layout (every slot rewritten every call; no memset needed):
  //   [0)     pairP float[512]    (2048 B, pad to 4096)
  //   [4096)  sposB float[512]    (2048 B)
  //   [6144)  zh    f16[8192*128] (2 MiB, 16B-aligned)
  float* pairP = (float*)(ws + 0);
  float* sposB = (float*)(ws + 4096);
  _Float16* zh = (_Float16*)(ws + 6144);

  fmicl_normalize<<<512, 1024, 0, stream>>>(z1, z2, zh, sposB);
  fmicl_pairwise<<<NBLK, 512, 0, stream>>>(zh, pairP);
  fmicl_reduce<<<1, 1024, 0, stream>>>(pairP, sposB, out);
}